// Round 1
// baseline (453.944 us; speedup 1.0000x reference)
//
#include <hip/hip_runtime.h>

// Problem constants (from reference): img (3,512,512) f32, theta (64,) f32.
// Output: (64, 3, 512, 512) f32 — rotated bilinear resample of img per theta.
constexpr int Cc = 3;
constexpr int Hh = 512;
constexpr int Ww = 512;
constexpr int Nn = 64;
constexpr int HW = Hh * Ww;

// Kernel 1: per-image cos/sin (64 entries) into workspace.
// Runs every launch (d_ws is re-poisoned before each timed call).
__global__ void precompute_cs(const float* __restrict__ theta,
                              float* __restrict__ cs) {
    int t = threadIdx.x;
    if (t < Nn) {
        float th = theta[t];
        cs[2 * t]     = cosf(th);
        cs[2 * t + 1] = sinf(th);
    }
}

// Kernel 2: each thread computes 4 adjacent pixels of one row for one image n,
// all 3 channels, and stores one float4 per channel (coalesced, 16B aligned).
__global__ __launch_bounds__(256) void rot_bilinear(
        const float* __restrict__ img,
        const float* __restrict__ cs,
        float* __restrict__ out)
{
    const int n  = blockIdx.y;
    const int p  = blockIdx.x * 256 + threadIdx.x;   // 0 .. H*W/4 - 1 (65535)
    const int i  = p >> 7;                           // row   0..511 (128 threads/row)
    const int j0 = (p & 127) << 2;                   // col base, multiple of 4

    const float c = cs[2 * n];
    const float s = cs[2 * n + 1];
    const float y = fmaf((float)i, 2.0f / 511.0f, -1.0f);

    float r0[4], r1[4], r2[4];

    #pragma unroll
    for (int e = 0; e < 4; ++e) {
        const int   j  = j0 + e;
        const float x  = fmaf((float)j, 2.0f / 511.0f, -1.0f);
        const float gx = c * x - s * y;
        const float gy = s * x + c * y;
        const float ix = fmaf(gx, 255.5f, 255.5f);   // (gx+1)*0.5*(W-1)
        const float iy = fmaf(gy, 255.5f, 255.5f);

        const float x0f = floorf(ix), y0f = floorf(iy);
        const float wx  = ix - x0f,   wy  = iy - y0f;
        const float x1f = x0f + 1.0f, y1f = y0f + 1.0f;

        // Validity: float compares on UNCLIPPED corner coords (matches reference).
        const bool vx0 = (x0f >= 0.0f) && (x0f <= 511.0f);
        const bool vx1 = (x1f >= 0.0f) && (x1f <= 511.0f);
        const bool vy0 = (y0f >= 0.0f) && (y0f <= 511.0f);
        const bool vy1 = (y1f >= 0.0f) && (y1f <= 511.0f);

        // Clamped integer indices (loads always in-bounds).
        const int xi0 = (int)fminf(fmaxf(x0f, 0.0f), 511.0f);
        const int xi1 = (int)fminf(fmaxf(x1f, 0.0f), 511.0f);
        const int yi0 = (int)fminf(fmaxf(y0f, 0.0f), 511.0f);
        const int yi1 = (int)fminf(fmaxf(y1f, 0.0f), 511.0f);

        float w00 = (1.0f - wx) * (1.0f - wy); if (!(vx0 && vy0)) w00 = 0.0f;
        float w01 = wx * (1.0f - wy);          if (!(vx1 && vy0)) w01 = 0.0f;
        float w10 = (1.0f - wx) * wy;          if (!(vx0 && vy1)) w10 = 0.0f;
        float w11 = wx * wy;                   if (!(vx1 && vy1)) w11 = 0.0f;

        const int b00 = yi0 * Ww + xi0;
        const int b01 = yi0 * Ww + xi1;
        const int b10 = yi1 * Ww + xi0;
        const int b11 = yi1 * Ww + xi1;

        r0[e] = img[b00]          * w00 + img[b01]          * w01
              + img[b10]          * w10 + img[b11]          * w11;
        r1[e] = img[HW + b00]     * w00 + img[HW + b01]     * w01
              + img[HW + b10]     * w10 + img[HW + b11]     * w11;
        r2[e] = img[2 * HW + b00] * w00 + img[2 * HW + b01] * w01
              + img[2 * HW + b10] * w10 + img[2 * HW + b11] * w11;
    }

    // out[((n*3 + c)*H + i)*W + j] = n*3*HW + c*HW + i*W + j
    const size_t base = (size_t)n * (size_t)(Cc * HW) + (size_t)i * Ww + j0;
    *(float4*)&out[base]          = make_float4(r0[0], r0[1], r0[2], r0[3]);
    *(float4*)&out[base + HW]     = make_float4(r1[0], r1[1], r1[2], r1[3]);
    *(float4*)&out[base + 2 * HW] = make_float4(r2[0], r2[1], r2[2], r2[3]);
}

extern "C" void kernel_launch(void* const* d_in, const int* in_sizes, int n_in,
                              void* d_out, int out_size, void* d_ws, size_t ws_size,
                              hipStream_t stream) {
    const float* img   = (const float*)d_in[0];
    const float* theta = (const float*)d_in[1];
    float*       out   = (float*)d_out;
    float*       cs    = (float*)d_ws;   // 2*Nn floats = 512 B

    precompute_cs<<<1, 64, 0, stream>>>(theta, cs);

    // H*W/4 = 65536 threads per image -> 256 blocks of 256; grid.y = n
    dim3 grid(HW / (256 * 4), Nn);
    rot_bilinear<<<grid, 256, 0, stream>>>(img, cs, out);
}

// Round 2
// 231.838 us; speedup vs baseline: 1.9580x; 1.9580x over previous
//
#include <hip/hip_runtime.h>

// img (3,512,512) f32, theta (64,) f32 -> out (64,3,512,512) f32
constexpr int Hh = 512;
constexpr int Ww = 512;
constexpr int Nn = 64;
constexpr int HW = Hh * Ww;
constexpr int TS  = 32;   // output tile side
constexpr int DIM = 48;   // staged source bbox max side (31*sqrt2 ~ 43.85 -> 44+x1+margins = 48)

// Kernel 1: per-image cos/sin into workspace (re-run every launch; ws re-poisoned).
__global__ void precompute_cs(const float* __restrict__ theta,
                              float* __restrict__ cs) {
    int t = threadIdx.x;
    if (t < Nn) {
        float th = theta[t];
        cs[2 * t]     = cosf(th);
        cs[2 * t + 1] = sinf(th);
    }
}

__device__ __forceinline__ int swzidx(int lr, int lc) {
    // row-dependent XOR on the column decorrelates LDS banks for rotated access.
    // Bijective within [0,48) since 47 = 0b101111 (low 3 bits free).
    return lr * DIM + (lc ^ (lr & 7));
}

__global__ __launch_bounds__(256) void rot_bilinear_lds(
        const float* __restrict__ img,
        const float* __restrict__ cs,
        float* __restrict__ out)
{
    __shared__ float4 lds[DIM * DIM];   // 36864 B

    const int n   = blockIdx.y;
    const int tix = blockIdx.x & 15;    // tile col
    const int tiy = blockIdx.x >> 4;    // tile row
    const int i0  = tiy * TS;
    const int j0  = tix * TS;

    const float c = cs[2 * n];
    const float s = cs[2 * n + 1];
    // ix = A + c*j - s*i ; iy = B + s*j + c*i   (exactly linear: step per px = c or s)
    const float A = 255.5f * (1.0f - c + s);
    const float B = 255.5f * (1.0f - s - c);

    // Source bbox from the 4 tile corners (linear map -> extremes at corners).
    const float j0f = (float)j0, j1f = (float)(j0 + TS - 1);
    const float i0f = (float)i0, i1f = (float)(i0 + TS - 1);
    float x00 = fmaf(c, j0f, fmaf(-s, i0f, A));
    float x01 = fmaf(c, j1f, fmaf(-s, i0f, A));
    float x10 = fmaf(c, j0f, fmaf(-s, i1f, A));
    float x11 = fmaf(c, j1f, fmaf(-s, i1f, A));
    float y00 = fmaf(s, j0f, fmaf(c, i0f, B));
    float y01 = fmaf(s, j1f, fmaf(c, i0f, B));
    float y10 = fmaf(s, j0f, fmaf(c, i1f, B));
    float y11 = fmaf(s, j1f, fmaf(c, i1f, B));
    const float minx = fminf(fminf(x00, x01), fminf(x10, x11));
    const float maxx = fmaxf(fmaxf(x00, x01), fmaxf(x10, x11));
    const float miny = fminf(fminf(y00, y01), fminf(y10, y11));
    const float maxy = fmaxf(fmaxf(y00, y01), fmaxf(y10, y11));

    // margins: -1 below, +2 above (floor+1 for x1, +/-1 rounding guard)
    const int cmin = (int)floorf(minx) - 1;
    const int cmax = (int)floorf(maxx) + 2;
    const int rmin = (int)floorf(miny) - 1;
    const int rmax = (int)floorf(maxy) + 2;
    const int c0s = min(max(cmin, 0), 511);
    const int c1s = min(max(cmax, 0), 511);
    const int r0s = min(max(rmin, 0), 511);
    const int r1s = min(max(rmax, 0), 511);
    const int Cn = c1s - c0s + 1;   // <= 48
    const int R  = r1s - r0s + 1;   // <= 48

    // ---- stage bbox (3 channels -> float4-padded LDS) ----
    const int tid = threadIdx.x;
    const int ty = tid >> 4, tx = tid & 15;
    for (int rr = ty; rr < R; rr += 16) {
        const float* p0 = img + (r0s + rr) * Ww + c0s;
        for (int cc = tx; cc < Cn; cc += 16) {
            float4 v;
            v.x = p0[cc];
            v.y = p0[HW + cc];
            v.z = p0[2 * HW + cc];
            v.w = 0.0f;
            lds[swzidx(rr, cc)] = v;
        }
    }
    __syncthreads();

    // ---- gather: each thread 4 adjacent px of one row; wave = 8 rows x 32 cols ----
    const int ir  = tid >> 3;          // 0..31 tile row
    const int jr4 = (tid & 7) << 2;    // tile col base (16B aligned store)
    const int gi  = i0 + ir;
    const float fi = (float)gi;

    float r0[4], r1[4], r2[4];

    #pragma unroll
    for (int e = 0; e < 4; ++e) {
        const float fj = (float)(j0 + jr4 + e);
        const float ix = fmaf(c, fj, fmaf(-s, fi, A));
        const float iy = fmaf(s, fj, fmaf(c, fi, B));

        const float x0f = floorf(ix), y0f = floorf(iy);
        const float wx  = ix - x0f,   wy  = iy - y0f;
        const float x1f = x0f + 1.0f, y1f = y0f + 1.0f;

        const bool vx0 = (x0f >= 0.0f) && (x0f <= 511.0f);
        const bool vx1 = (x1f >= 0.0f) && (x1f <= 511.0f);
        const bool vy0 = (y0f >= 0.0f) && (y0f <= 511.0f);
        const bool vy1 = (y1f >= 0.0f) && (y1f <= 511.0f);

        // clamped global indices, then LDS-relative (guaranteed inside staged bbox)
        const int xi0 = min(max((int)x0f, 0), 511) - c0s;
        const int xi1 = min(max((int)x0f + 1, 0), 511) - c0s;
        const int yi0 = min(max((int)y0f, 0), 511) - r0s;
        const int yi1 = min(max((int)y0f + 1, 0), 511) - r0s;

        float w00 = (1.0f - wx) * (1.0f - wy); if (!(vx0 && vy0)) w00 = 0.0f;
        float w01 = wx * (1.0f - wy);          if (!(vx1 && vy0)) w01 = 0.0f;
        float w10 = (1.0f - wx) * wy;          if (!(vx0 && vy1)) w10 = 0.0f;
        float w11 = wx * wy;                   if (!(vx1 && vy1)) w11 = 0.0f;

        const float4 v00 = lds[swzidx(yi0, xi0)];
        const float4 v01 = lds[swzidx(yi0, xi1)];
        const float4 v10 = lds[swzidx(yi1, xi0)];
        const float4 v11 = lds[swzidx(yi1, xi1)];

        r0[e] = v00.x * w00 + v01.x * w01 + v10.x * w10 + v11.x * w11;
        r1[e] = v00.y * w00 + v01.y * w01 + v10.y * w10 + v11.y * w11;
        r2[e] = v00.z * w00 + v01.z * w01 + v10.z * w10 + v11.z * w11;
    }

    const size_t base = (size_t)n * (size_t)(3 * HW) + (size_t)gi * Ww + (j0 + jr4);
    *(float4*)&out[base]          = make_float4(r0[0], r0[1], r0[2], r0[3]);
    *(float4*)&out[base + HW]     = make_float4(r1[0], r1[1], r1[2], r1[3]);
    *(float4*)&out[base + 2 * HW] = make_float4(r2[0], r2[1], r2[2], r2[3]);
}

extern "C" void kernel_launch(void* const* d_in, const int* in_sizes, int n_in,
                              void* d_out, int out_size, void* d_ws, size_t ws_size,
                              hipStream_t stream) {
    const float* img   = (const float*)d_in[0];
    const float* theta = (const float*)d_in[1];
    float*       out   = (float*)d_out;
    float*       cs    = (float*)d_ws;   // 512 B

    precompute_cs<<<1, 64, 0, stream>>>(theta, cs);

    dim3 grid((Hh / TS) * (Ww / TS), Nn);   // (256, 64)
    rot_bilinear_lds<<<grid, 256, 0, stream>>>(img, cs, out);
}

// Round 9
// 220.973 us; speedup vs baseline: 2.0543x; 1.0492x over previous
//
#include <hip/hip_runtime.h>

// img (3,512,512) f32, theta (64,) f32 -> out (64,3,512,512) f32
typedef float f4 __attribute__((ext_vector_type(4)));

constexpr int Hh = 512;
constexpr int Ww = 512;
constexpr int Nn = 64;
constexpr int HW = Hh * Ww;
constexpr int TS   = 32;   // output tile side
constexpr int ROWS = 48;   // max staged rows: ceil(31*sqrt2)+4 = 48
constexpr int COLS = 52;   // max staged cols 48 + 3 (float4 alignment of col base)

// Kernel 1: per-image cos/sin into workspace (ws re-poisoned every launch).
__global__ void precompute_cs(const float* __restrict__ theta,
                              float* __restrict__ cs) {
    int t = threadIdx.x;
    if (t < Nn) {
        float th = theta[t];
        cs[2 * t]     = cosf(th);
        cs[2 * t + 1] = sinf(th);
    }
}

// XOR swizzle, mask &3: bijective within [0,COLS) since lc<=51 -> lc^3 <= 51
// (flips only low 2 bits). NOTE: &7 overflowed the 52-wide row for lc>=48 and
// collided with the next row's slots -> data corruption (round-6 fail).
__device__ __forceinline__ int swz(int lr, int lc) {
    return lr * COLS + (lc ^ (lr & 3));
}

__global__ __launch_bounds__(256) void rot_bilinear_lds(
        const float* __restrict__ img,
        const float* __restrict__ cs,
        float* __restrict__ out)
{
    __shared__ f4 lds[ROWS * COLS];   // 39,936 B -> 4 blocks/CU

    const int n   = blockIdx.y;
    const int tix = blockIdx.x & 15;
    const int tiy = blockIdx.x >> 4;
    const int i0  = tiy * TS;
    const int j0  = tix * TS;

    const float c = cs[2 * n];
    const float s = cs[2 * n + 1];
    // ix = A + c*j - s*i ; iy = B + s*j + c*i  (exact linear map)
    const float A = 255.5f * (1.0f - c + s);
    const float B = 255.5f * (1.0f - s - c);

    // Source bbox from the 4 tile corners (linear -> extremes at corners).
    const float j0f = (float)j0, j1f = (float)(j0 + TS - 1);
    const float i0f = (float)i0, i1f = (float)(i0 + TS - 1);
    const float x00 = fmaf(c, j0f, fmaf(-s, i0f, A));
    const float x01 = fmaf(c, j1f, fmaf(-s, i0f, A));
    const float x10 = fmaf(c, j0f, fmaf(-s, i1f, A));
    const float x11 = fmaf(c, j1f, fmaf(-s, i1f, A));
    const float y00 = fmaf(s, j0f, fmaf(c, i0f, B));
    const float y01 = fmaf(s, j1f, fmaf(c, i0f, B));
    const float y10 = fmaf(s, j0f, fmaf(c, i1f, B));
    const float y11 = fmaf(s, j1f, fmaf(c, i1f, B));
    const float minx = fminf(fminf(x00, x01), fminf(x10, x11));
    const float maxx = fmaxf(fmaxf(x00, x01), fmaxf(x10, x11));
    const float miny = fminf(fminf(y00, y01), fminf(y10, y11));
    const float maxy = fmaxf(fmaxf(y00, y01), fmaxf(y10, y11));

    const int cmin = (int)floorf(minx) - 1;   // margin: floor-1 below, +2 above
    const int cmax = (int)floorf(maxx) + 2;
    const int rmin = (int)floorf(miny) - 1;
    const int rmax = (int)floorf(maxy) + 2;
    const int c0s = min(max(cmin, 0), 511);
    const int c1s = min(max(cmax, 0), 511);
    const int r0s = min(max(rmin, 0), 511);
    const int r1s = min(max(rmax, 0), 511);
    const int c0a = c0s & ~3;                 // float4-aligned col base
    const int width = c1s - c0a + 1;          // <= 51
    const int R     = r1s - r0s + 1;          // <= 48
    // Block-uniform: no corner of any px in this tile can be invalid or need clamping.
    const bool interior = (cmin >= 0) & (rmin >= 0) & (cmax <= 511) & (rmax <= 511);

    // ---- stage bbox: float4 global loads per channel, AoS-transpose into LDS ----
    // c0a+cA is a multiple of 4 and <= 511, hence <= 508: every chunk ends
    // at column <= 511 -> no cross-row or OOB reads.
    const int tid = threadIdx.x;
    const int ty = tid >> 4, tx = tid & 15;
    const int cA = tx << 2;                   // chunk col offset (aligned)
    if (cA < width) {
        for (int rr = ty; rr < R; rr += 16) {
            const float* p = img + (r0s + rr) * Ww + c0a + cA;
            const f4 a0 = *(const f4*)p;
            const f4 a1 = *(const f4*)(p + HW);
            const f4 a2 = *(const f4*)(p + 2 * HW);
            #pragma unroll
            for (int e = 0; e < 4; ++e) {
                f4 v;
                v.x = a0[e]; v.y = a1[e]; v.z = a2[e]; v.w = 0.0f;
                lds[swz(rr, cA + e)] = v;
            }
        }
    }
    __syncthreads();

    // ---- gather: wave = 8 rows x 32 cols; each thread 4 adjacent px ----
    const int ir  = tid >> 3;
    const int gj0 = j0 + ((tid & 7) << 2);
    const int gi  = i0 + ir;
    const float fi  = (float)gi;
    const float ixr = fmaf(-s, fi, A);
    const float iyr = fmaf( c, fi, B);

    f4 res[4];

    if (interior) {
        #pragma unroll
        for (int e = 0; e < 4; ++e) {
            const float fj = (float)(gj0 + e);
            const float ix = fmaf(c, fj, ixr);
            const float iy = fmaf(s, fj, iyr);
            const float x0f = floorf(ix), y0f = floorf(iy);
            const float wx = ix - x0f,  wy = iy - y0f;
            const int xi = (int)x0f - c0a;     // x0f >= 1 when interior
            const int yi = (int)y0f - r0s;
            const float u0 = 1.0f - wx, v0 = 1.0f - wy;
            const float w00 = u0 * v0, w01 = wx * v0, w10 = u0 * wy, w11 = wx * wy;
            const int m0 = yi & 3, m1 = (yi + 1) & 3;
            const int rb0 = yi * COLS, rb1 = rb0 + COLS;
            const f4 v00 = lds[rb0 + ( xi      ^ m0)];
            const f4 v01 = lds[rb0 + ((xi + 1) ^ m0)];
            const f4 v10 = lds[rb1 + ( xi      ^ m1)];
            const f4 v11 = lds[rb1 + ((xi + 1) ^ m1)];
            res[e] = v00 * w00 + v01 * w01 + v10 * w10 + v11 * w11;   // v_pk_fma_f32
        }
    } else {
        #pragma unroll
        for (int e = 0; e < 4; ++e) {
            const float fj = (float)(gj0 + e);
            const float ix = fmaf(c, fj, ixr);
            const float iy = fmaf(s, fj, iyr);
            const float x0f = floorf(ix), y0f = floorf(iy);
            const float wx = ix - x0f,  wy = iy - y0f;
            const float x1f = x0f + 1.0f, y1f = y0f + 1.0f;

            const bool vx0 = (x0f >= 0.0f) && (x0f <= 511.0f);
            const bool vx1 = (x1f >= 0.0f) && (x1f <= 511.0f);
            const bool vy0 = (y0f >= 0.0f) && (y0f <= 511.0f);
            const bool vy1 = (y1f >= 0.0f) && (y1f <= 511.0f);

            // Clamped indices always land inside the staged bbox (proof: x0f>=cmin,
            // x0f+1<=cmax, so clamp(.,0,511) is within [c0s..c1s]; same for y).
            const int xi0 = min(max((int)x0f,     0), 511) - c0a;
            const int xi1 = min(max((int)x0f + 1, 0), 511) - c0a;
            const int yi0 = min(max((int)y0f,     0), 511) - r0s;
            const int yi1 = min(max((int)y0f + 1, 0), 511) - r0s;

            float w00 = (1.0f - wx) * (1.0f - wy); if (!(vx0 && vy0)) w00 = 0.0f;
            float w01 = wx * (1.0f - wy);          if (!(vx1 && vy0)) w01 = 0.0f;
            float w10 = (1.0f - wx) * wy;          if (!(vx0 && vy1)) w10 = 0.0f;
            float w11 = wx * wy;                   if (!(vx1 && vy1)) w11 = 0.0f;

            const f4 v00 = lds[swz(yi0, xi0)];
            const f4 v01 = lds[swz(yi0, xi1)];
            const f4 v10 = lds[swz(yi1, xi0)];
            const f4 v11 = lds[swz(yi1, xi1)];
            res[e] = v00 * w00 + v01 * w01 + v10 * w10 + v11 * w11;
        }
    }

    // ---- coalesced float4 stores, one per channel ----
    const size_t base = (size_t)n * (size_t)(3 * HW) + (size_t)gi * Ww + gj0;
    *(float4*)&out[base]          = make_float4(res[0].x, res[1].x, res[2].x, res[3].x);
    *(float4*)&out[base + HW]     = make_float4(res[0].y, res[1].y, res[2].y, res[3].y);
    *(float4*)&out[base + 2 * HW] = make_float4(res[0].z, res[1].z, res[2].z, res[3].z);
}

extern "C" void kernel_launch(void* const* d_in, const int* in_sizes, int n_in,
                              void* d_out, int out_size, void* d_ws, size_t ws_size,
                              hipStream_t stream) {
    const float* img   = (const float*)d_in[0];
    const float* theta = (const float*)d_in[1];
    float*       out   = (float*)d_out;
    float*       cs    = (float*)d_ws;   // 512 B

    precompute_cs<<<1, 64, 0, stream>>>(theta, cs);

    dim3 grid((Hh / TS) * (Ww / TS), Nn);   // (256, 64)
    rot_bilinear_lds<<<grid, 256, 0, stream>>>(img, cs, out);
}